// Round 8
// baseline (465.138 us; speedup 1.0000x reference)
//
#include <hip/hip_runtime.h>
#include <hip/hip_bf16.h>
#include <stdint.h>

#define NSK 1000
#define TT  200
#define BB  64
#define NROW (BB * TT)      // 12800
#define NOUT (BB * (TT-1))  // 12736
#define CH  8               // scan pipeline depth (steps)
#define RW  8               // scan Mv rows per wave
#define REP 8               // diagnostic: repeat each kernel body 8x (idempotent)

__device__ __forceinline__ float lane_bcast(float v, int l) {
  return __uint_as_float(__builtin_amdgcn_readlane(__float_as_uint(v), l));
}
__device__ __forceinline__ float bflo(unsigned u){ return __uint_as_float(u << 16); }
__device__ __forceinline__ float bfhi(unsigned u){ return __uint_as_float(u & 0xffff0000u); }
__device__ __forceinline__ unsigned pack2(float a, float b) {
  __hip_bfloat16 ha = __float2bfloat16(a), hb = __float2bfloat16(b);
  return (unsigned)*(unsigned short*)&ha | ((unsigned)*(unsigned short*)&hb << 16);
}
__device__ __forceinline__ float frcp(float x) { return __builtin_amdgcn_rcpf(x); }
__device__ __forceinline__ float sigm(float x) { return frcp(1.f + __expf(-x)); }
__device__ __forceinline__ float tanh_fast(float x) {
  return fmaf(-2.f, frcp(1.f + __expf(2.f * x)), 1.f);   // 1 - 2/(1+e^2x)
}

// Pass A (diagnostic x8): w = softmax(k Mk^T), e = sigm(v eW^T+eb), a = tanh(v aW^T+ab)
__global__ __launch_bounds__(256) void wea_kernel(
    const int* __restrict__ skills, const int* __restrict__ responses,
    const float* __restrict__ k_emb, const float* __restrict__ v_emb,
    const float* __restrict__ Mk, const float* __restrict__ eW,
    const float* __restrict__ eb, const float* __restrict__ aW,
    const float* __restrict__ ab,
    float* __restrict__ w_ws, float* __restrict__ e_ws, float* __restrict__ a_ws,
    int zero)
{
  __shared__ unsigned sw[3 * 64 * 40];               // 30720 B
  const int tid = threadIdx.x;
  for (int ch = tid; ch < 1536; ch += 256) {         // 512 chunks per matrix
    const int mat = ch >> 9;
    const int rem = ch & 511;
    const int j = rem >> 3, cc = rem & 7;
    const float4* src = (mat == 0) ? (const float4*)Mk
                      : (mat == 1) ? (const float4*)eW : (const float4*)aW;
    const float4 f0 = src[j * 16 + cc * 2];
    const float4 f1 = src[j * 16 + cc * 2 + 1];
    uint4 pk;
    pk.x = pack2(f0.x, f0.y); pk.y = pack2(f0.z, f0.w);
    pk.z = pack2(f1.x, f1.y); pk.w = pack2(f1.z, f1.w);
    *(uint4*)&sw[mat * 2560 + j * 40 + ((cc + j) & 7) * 4] = pk;
  }
  __syncthreads();

  const int wave = tid >> 6, lane = tid & 63;
  const float ebl = eb[lane], abl = ab[lane];
  const int r0 = (blockIdx.x * 4 + wave) * 2;        // grid exact: 1600*4*2 = 12800

  #pragma unroll 1
  for (int rep = 0; rep < REP; ++rep) {
    const float z = (float)(zero * rep);             // opaque 0: keeps reps live
    float kv[2], vv[2];
    #pragma unroll
    for (int i = 0; i < 2; ++i) {
      const int sk = skills[r0 + i];
      int rr = responses[r0 + i]; rr = (rr > -1) ? rr : 0;   // masked_r
      kv[i] = k_emb[(size_t)sk * 64 + lane];
      vv[i] = v_emb[(size_t)(sk + NSK * rr) * 64 + lane];
    }

    float accK[2] = {z, z}, accE[2] = {z, z}, accA[2] = {z, z};
    #pragma unroll 1
    for (int h = 0; h < 2; ++h) {                    // halves: 4 chunks (32 dims) each
      uint4 qm[4], qe[4], qa[4];
      #pragma unroll
      for (int c = 0; c < 4; ++c) {
        const int off = lane * 40 + (((h * 4 + c) + lane) & 7) * 4;
        qm[c] = *(const uint4*)&sw[off];
        qe[c] = *(const uint4*)&sw[2560 + off];
        qa[c] = *(const uint4*)&sw[5120 + off];
      }
      #pragma unroll
      for (int i = 0; i < 2; ++i) {
        #pragma unroll
        for (int c = 0; c < 4; ++c) {
          const unsigned um[4] = {qm[c].x, qm[c].y, qm[c].z, qm[c].w};
          const unsigned ue[4] = {qe[c].x, qe[c].y, qe[c].z, qe[c].w};
          const unsigned ua[4] = {qa[c].x, qa[c].y, qa[c].z, qa[c].w};
          #pragma unroll
          for (int m = 0; m < 4; ++m) {
            const int d0 = (h * 4 + c) * 8 + 2 * m;
            const float k0 = lane_bcast(kv[i], d0), k1 = lane_bcast(kv[i], d0 + 1);
            const float v0 = lane_bcast(vv[i], d0), v1 = lane_bcast(vv[i], d0 + 1);
            accK[i] = fmaf(k0, bflo(um[m]), accK[i]);
            accK[i] = fmaf(k1, bfhi(um[m]), accK[i]);
            accE[i] = fmaf(v0, bflo(ue[m]), accE[i]);
            accE[i] = fmaf(v1, bfhi(ue[m]), accE[i]);
            accA[i] = fmaf(v0, bflo(ua[m]), accA[i]);
            accA[i] = fmaf(v1, bfhi(ua[m]), accA[i]);
          }
        }
      }
    }

    #pragma unroll
    for (int i = 0; i < 2; ++i) {
      const int row = r0 + i;
      float mx = accK[i];
      #pragma unroll
      for (int off = 32; off; off >>= 1) mx = fmaxf(mx, __shfl_xor(mx, off));
      float ex = __expf(accK[i] - mx);
      float sm = ex;
      #pragma unroll
      for (int off = 32; off; off >>= 1) sm += __shfl_xor(sm, off);
      w_ws[(size_t)row * 64 + lane] = ex * frcp(sm);
      e_ws[(size_t)row * 64 + lane] = sigm(accE[i] + ebl);
      a_ws[(size_t)row * 64 + lane] = tanh_fast(accA[i] + abl);
    }
  }
}

// ---- scan helpers ----
__device__ __forceinline__ void load_chunk(
    const float* __restrict__ wr, const float* __restrict__ er,
    const float* __restrict__ ar, int t0, int wl, int lane,
    float* wb, float* ebf, float* abf)
{
  #pragma unroll
  for (int k = 0; k < CH; ++k) {
    wb[k]  = wr[(t0 + k) * 64 + wl];
    ebf[k] = er[(t0 + k) * 64 + lane];
    abf[k] = ar[(t0 + k) * 64 + lane];
  }
}

__device__ __forceinline__ void compute_chunk(
    float* Mv, const float* wb, const float* ebf, const float* abf,
    int t0, int part, int lane, float* __restrict__ pr)
{
  #pragma unroll
  for (int k = 0; k < CH; ++k) {
    const float wv = wb[k], ev = ebf[k], av = abf[k];
    float rp = 0.f;
    #pragma unroll
    for (int i = 0; i < RW; ++i) {
      float wm = lane_bcast(wv, i);        // w[m0+i] sits in lane i (0..7)
      rp = fmaf(wm, Mv[i], rp);            // read uses PRE-update Mv
      float tp = fmaf(-ev, Mv[i], av);     // a - e*Mv
      Mv[i] = fmaf(wm, tp, Mv[i]);         // Mv += w*(a - e*Mv)
    }
    pr[(t0 + k) * 512 + part * 64 + lane] = rp;
  }
}

// Pass B (diagnostic x8): sequential scan; 2 blocks x 4 waves x 8 rows per batch.
__global__ __launch_bounds__(256) void scan_kernel(
    const float* __restrict__ Mv0,
    const float* __restrict__ w_ws, const float* __restrict__ e_ws,
    const float* __restrict__ a_ws, float* __restrict__ part_ws, int zero)
{
  const int b    = blockIdx.x >> 1;
  const int s    = blockIdx.x & 1;
  const int wave = threadIdx.x >> 6;
  const int lane = threadIdx.x & 63;
  const int m0   = s * 32 + wave * RW;
  const int part = s * 4 + wave;
  const int wl   = m0 + (lane & (RW - 1));

  const float* wr = w_ws + (size_t)b * TT * 64;
  const float* er = e_ws + (size_t)b * TT * 64;
  const float* ar = a_ws + (size_t)b * TT * 64;
  float* pr = part_ws + (size_t)b * TT * 512;

  #pragma unroll 1
  for (int rep = 0; rep < REP; ++rep) {
    const float z = (float)(zero * rep);
    float Mv[RW];
    #pragma unroll
    for (int i = 0; i < RW; ++i) Mv[i] = Mv0[(size_t)(m0 + i) * 64 + lane] + z;

    float wb0[CH], eb0[CH], ab0[CH];
    float wb1[CH], eb1[CH], ab1[CH];
    load_chunk(wr, er, ar, 0, wl, lane, wb0, eb0, ab0);
    for (int ch = 0; ch < TT / CH; ch += 2) {
      if ((ch + 1) * CH < TT)
        load_chunk(wr, er, ar, (ch + 1) * CH, wl, lane, wb1, eb1, ab1);
      compute_chunk(Mv, wb0, eb0, ab0, ch * CH, part, lane, pr);
      if ((ch + 2) * CH < TT)
        load_chunk(wr, er, ar, (ch + 2) * CH, wl, lane, wb0, eb0, ab0);
      if ((ch + 1) * CH < TT)
        compute_chunk(Mv, wb1, eb1, ab1, (ch + 1) * CH, part, lane, pr);
    }
  }
}

// Pass C (diagnostic x8): read = sum 8 partials; f = tanh([read,k] fW^T + fb); p = sigm(f pW + pb)
__global__ __launch_bounds__(256) void fp_kernel(
    const int* __restrict__ skills, const float* __restrict__ k_emb,
    const float* __restrict__ fW, const float* __restrict__ fb,
    const float* __restrict__ pW, const float* __restrict__ pb,
    const float* __restrict__ part_ws, float* __restrict__ out, int zero)
{
  __shared__ unsigned sf[64 * 72];                   // 18432 B
  const int tid = threadIdx.x;
  for (int ch = tid; ch < 1024; ch += 256) {         // 16 chunks per row
    const int j = ch >> 4, cc = ch & 15;
    const float4 f0 = ((const float4*)fW)[j * 32 + cc * 2];
    const float4 f1 = ((const float4*)fW)[j * 32 + cc * 2 + 1];
    uint4 pk;
    pk.x = pack2(f0.x, f0.y); pk.y = pack2(f0.z, f0.w);
    pk.z = pack2(f1.x, f1.y); pk.w = pack2(f1.z, f1.w);
    *(uint4*)&sf[j * 72 + ((cc + j) & 15) * 4] = pk;
  }
  __syncthreads();

  const int wave = tid >> 6, lane = tid & 63;
  const float fbl = fb[lane], pwl = pW[lane], pb0 = pb[0];
  const int p = blockIdx.x * 4 + wave;               // pair id, grid exact: 1592*4 = 6368

  #pragma unroll 1
  for (int rep = 0; rep < REP; ++rep) {
    const float z = (float)(zero * rep);
    float pc[2][8], kc[2];
    int bsave[2], tsave[2];
    #pragma unroll
    for (int i = 0; i < 2; ++i) {
      const unsigned idx = 2u * p + i;
      const unsigned b = idx / 199u;
      const int row = (int)(idx + b + 1u);
      bsave[i] = (int)b; tsave[i] = (int)(idx - b * 199u);
      const float* pp = part_ws + (size_t)row * 512;
      #pragma unroll
      for (int q = 0; q < 8; ++q) pc[i][q] = pp[q * 64 + lane];
      kc[i] = k_emb[(size_t)skills[row] * 64 + lane];
    }
    float rv[2];
    #pragma unroll
    for (int i = 0; i < 2; ++i)
      rv[i] = ((pc[i][0] + pc[i][1]) + (pc[i][2] + pc[i][3]))
            + ((pc[i][4] + pc[i][5]) + (pc[i][6] + pc[i][7]));

    float acc[2] = {fbl + z, fbl + z};
    #pragma unroll 1
    for (int h = 0; h < 4; ++h) {                    // quarters: 4 chunks (32 inputs) each
      uint4 qf[4];
      #pragma unroll
      for (int c = 0; c < 4; ++c)
        qf[c] = *(const uint4*)&sf[lane * 72 + (((h * 4 + c) + lane) & 15) * 4];
      #pragma unroll
      for (int i = 0; i < 2; ++i) {
        #pragma unroll
        for (int c = 0; c < 4; ++c) {
          const unsigned uu[4] = {qf[c].x, qf[c].y, qf[c].z, qf[c].w};
          #pragma unroll
          for (int m = 0; m < 4; ++m) {
            const int d0 = (h * 4 + c) * 8 + 2 * m;    // 0..126
            const float s0 = (d0 < 64) ? lane_bcast(rv[i], d0) : lane_bcast(kc[i], d0 - 64);
            const float s1 = (d0 + 1 < 64) ? lane_bcast(rv[i], d0 + 1) : lane_bcast(kc[i], d0 - 63);
            acc[i] = fmaf(s0, bflo(uu[m]), acc[i]);
            acc[i] = fmaf(s1, bfhi(uu[m]), acc[i]);
          }
        }
      }
    }

    float f0 = tanh_fast(acc[0]) * pwl;
    float f1 = tanh_fast(acc[1]) * pwl;
    #pragma unroll
    for (int off = 32; off; off >>= 1) {
      f0 += __shfl_xor(f0, off);
      f1 += __shfl_xor(f1, off);
    }
    if (lane == 0) {
      out[(size_t)bsave[0] * (TT - 1) + tsave[0]] = sigm(f0 + pb0);
      out[(size_t)bsave[1] * (TT - 1) + tsave[1]] = sigm(f1 + pb0);
    }
  }
}

extern "C" void kernel_launch(void* const* d_in, const int* in_sizes, int n_in,
                              void* d_out, int out_size, void* d_ws, size_t ws_size,
                              hipStream_t stream) {
  const int* skills    = (const int*)d_in[0];
  const int* responses = (const int*)d_in[1];
  const float* k_emb   = (const float*)d_in[2];
  const float* v_emb   = (const float*)d_in[3];
  const float* Mk      = (const float*)d_in[4];
  const float* Mv0     = (const float*)d_in[5];
  const float* fW      = (const float*)d_in[6];
  const float* fb      = (const float*)d_in[7];
  const float* eW      = (const float*)d_in[8];
  const float* eb      = (const float*)d_in[9];
  const float* aW      = (const float*)d_in[10];
  const float* ab      = (const float*)d_in[11];
  const float* pW      = (const float*)d_in[12];
  const float* pb      = (const float*)d_in[13];

  // fp32 scratch: w | e | a (B*T*64 each) | read-partials (B*T*512) ~= 36 MB
  float* w_ws    = (float*)d_ws;
  float* e_ws    = w_ws + (size_t)BB * TT * 64;
  float* a_ws    = e_ws + (size_t)BB * TT * 64;
  float* part_ws = a_ws + (size_t)BB * TT * 64;

  wea_kernel<<<dim3(NROW / 8), 256, 0, stream>>>(
      skills, responses, k_emb, v_emb, Mk, eW, eb, aW, ab, w_ws, e_ws, a_ws, 0);
  scan_kernel<<<dim3(BB * 2), 256, 0, stream>>>(Mv0, w_ws, e_ws, a_ws, part_ws, 0);
  fp_kernel<<<dim3(NOUT / 8), 256, 0, stream>>>(
      skills, k_emb, fW, fb, pW, pb, part_ws, (float*)d_out, 0);
}

// Round 9
// 135.191 us; speedup vs baseline: 3.4406x; 3.4406x over previous
//
#include <hip/hip_runtime.h>
#include <hip/hip_bf16.h>
#include <stdint.h>

#define NSK 1000
#define TT  200
#define BB  64
#define NROW (BB * TT)      // 12800
#define NOUT (BB * (TT-1))  // 12736
#define CH  8               // scan pipeline depth (steps)
#define RW  8               // scan Mv rows per wave

__device__ __forceinline__ float lane_bcast(float v, int l) {
  return __uint_as_float(__builtin_amdgcn_readlane(__float_as_uint(v), l));
}
__device__ __forceinline__ unsigned ulane_bcast(unsigned v, int l) {
  return __builtin_amdgcn_readlane(v, l);
}
__device__ __forceinline__ float frcp(float x) { return __builtin_amdgcn_rcpf(x); }
__device__ __forceinline__ float sigm(float x) { return frcp(1.f + __expf(-x)); }
__device__ __forceinline__ float tanh_fast(float x) {
  return fmaf(-2.f, frcp(1.f + __expf(2.f * x)), 1.f);   // 1 - 2/(1+e^2x)
}

// ---- packed-f16 pair helpers (v_dot2_f32_f16 path; exact-ish fallback if absent) ----
typedef _Float16 half2v __attribute__((ext_vector_type(2)));
union H2U { unsigned u; half2v h; };
__device__ __forceinline__ unsigned pack2h(float a, float b) {
  H2U x; x.h = (half2v){(_Float16)a, (_Float16)b}; return x.u;
}
__device__ __forceinline__ float dot2h(unsigned sp, unsigned wp, float acc) {
#if __has_builtin(__builtin_amdgcn_fdot2)
  H2U s, w; s.u = sp; w.u = wp;
  return __builtin_amdgcn_fdot2(s.h, w.h, acc, false);
#else
  H2U s, w; s.u = sp; w.u = wp;
  return fmaf((float)s.h.y, (float)w.h.y, fmaf((float)s.h.x, (float)w.h.x, acc));
#endif
}
// build packed-pair broadcast register: lane L (0..31) holds f16 pair (v[2L], v[2L+1])
__device__ __forceinline__ unsigned pack_pairs(float v) {
  const int lane = threadIdx.x & 63;
  float a = __shfl(v, 2 * lane);       // wraps mod 64; lanes 0..31 cover all pairs
  float b = __shfl(v, 2 * lane + 1);
  return pack2h(a, b);
}

// Pass A: w = softmax(k Mk^T), e = sigm(v eW^T+eb), a = tanh(v aW^T+ab); 2 rows/wave.
// Weights f16-pair-packed in LDS, padded row stride 40 dwords; inner loop = readlane+dot2.
__global__ __launch_bounds__(256) void wea_kernel(
    const int* __restrict__ skills, const int* __restrict__ responses,
    const float* __restrict__ k_emb, const float* __restrict__ v_emb,
    const float* __restrict__ Mk, const float* __restrict__ eW,
    const float* __restrict__ eb, const float* __restrict__ aW,
    const float* __restrict__ ab,
    float* __restrict__ w_ws, float* __restrict__ e_ws, float* __restrict__ a_ws)
{
  __shared__ unsigned sw[3 * 64 * 40];               // 30720 B
  const int tid = threadIdx.x;
  for (int ch = tid; ch < 1536; ch += 256) {         // 512 8-input chunks per matrix
    const int mat = ch >> 9;
    const int rem = ch & 511;
    const int j = rem >> 3, cc = rem & 7;
    const float4* src = (mat == 0) ? (const float4*)Mk
                      : (mat == 1) ? (const float4*)eW : (const float4*)aW;
    const float4 f0 = src[j * 16 + cc * 2];
    const float4 f1 = src[j * 16 + cc * 2 + 1];
    uint4 pk;
    pk.x = pack2h(f0.x, f0.y); pk.y = pack2h(f0.z, f0.w);
    pk.z = pack2h(f1.x, f1.y); pk.w = pack2h(f1.z, f1.w);
    *(uint4*)&sw[mat * 2560 + j * 40 + ((cc + j) & 7) * 4] = pk;
  }
  __syncthreads();

  const int wave = tid >> 6, lane = tid & 63;
  const float ebl = eb[lane], abl = ab[lane];
  const int r0 = (blockIdx.x * 4 + wave) * 2;        // grid exact: 1600*4*2 = 12800

  float kv[2], vv[2];
  #pragma unroll
  for (int i = 0; i < 2; ++i) {
    const int sk = skills[r0 + i];
    int rr = responses[r0 + i]; rr = (rr > -1) ? rr : 0;   // masked_r
    kv[i] = k_emb[(size_t)sk * 64 + lane];
    vv[i] = v_emb[(size_t)(sk + NSK * rr) * 64 + lane];
  }
  unsigned kp[2], vp[2];
  #pragma unroll
  for (int i = 0; i < 2; ++i) { kp[i] = pack_pairs(kv[i]); vp[i] = pack_pairs(vv[i]); }

  float accK[2] = {0.f, 0.f}, accE[2] = {0.f, 0.f}, accA[2] = {0.f, 0.f};
  #pragma unroll 1
  for (int h = 0; h < 2; ++h) {                      // halves: 4 uint4 chunks (32 dims)
    uint4 qm[4], qe[4], qa[4];
    #pragma unroll
    for (int c = 0; c < 4; ++c) {
      const int off = lane * 40 + (((h * 4 + c) + lane) & 7) * 4;
      qm[c] = *(const uint4*)&sw[off];
      qe[c] = *(const uint4*)&sw[2560 + off];
      qa[c] = *(const uint4*)&sw[5120 + off];
    }
    #pragma unroll
    for (int i = 0; i < 2; ++i) {
      #pragma unroll
      for (int c = 0; c < 4; ++c) {
        const unsigned um[4] = {qm[c].x, qm[c].y, qm[c].z, qm[c].w};
        const unsigned ue[4] = {qe[c].x, qe[c].y, qe[c].z, qe[c].w};
        const unsigned ua[4] = {qa[c].x, qa[c].y, qa[c].z, qa[c].w};
        #pragma unroll
        for (int m = 0; m < 4; ++m) {
          const int idx = (h * 4 + c) * 4 + m;       // pair index 0..31
          const unsigned spk = ulane_bcast(kp[i], idx);
          const unsigned spv = ulane_bcast(vp[i], idx);
          accK[i] = dot2h(spk, um[m], accK[i]);
          accE[i] = dot2h(spv, ue[m], accE[i]);
          accA[i] = dot2h(spv, ua[m], accA[i]);
        }
      }
    }
  }

  #pragma unroll
  for (int i = 0; i < 2; ++i) {
    const int row = r0 + i;
    float mx = accK[i];
    #pragma unroll
    for (int off = 32; off; off >>= 1) mx = fmaxf(mx, __shfl_xor(mx, off));
    float ex = __expf(accK[i] - mx);
    float sm = ex;
    #pragma unroll
    for (int off = 32; off; off >>= 1) sm += __shfl_xor(sm, off);
    w_ws[(size_t)row * 64 + lane] = ex * frcp(sm);
    e_ws[(size_t)row * 64 + lane] = sigm(accE[i] + ebl);
    a_ws[(size_t)row * 64 + lane] = tanh_fast(accA[i] + abl);
  }
}

// ---- scan helpers ----
__device__ __forceinline__ void load_chunk(
    const float* __restrict__ wr, const float* __restrict__ er,
    const float* __restrict__ ar, int t0, int wl, int lane,
    float* wb, float* ebf, float* abf)
{
  #pragma unroll
  for (int k = 0; k < CH; ++k) {
    wb[k]  = wr[(t0 + k) * 64 + wl];
    ebf[k] = er[(t0 + k) * 64 + lane];
    abf[k] = ar[(t0 + k) * 64 + lane];
  }
}

__device__ __forceinline__ void compute_chunk(
    float* Mv, const float* wb, const float* ebf, const float* abf,
    float* __restrict__ red, int wave, int lane)
{
  #pragma unroll
  for (int k = 0; k < CH; ++k) {
    const float wv = wb[k], ev = ebf[k], av = abf[k];
    float rp = 0.f;
    #pragma unroll
    for (int i = 0; i < RW; ++i) {
      float wm = lane_bcast(wv, i);        // w[m0+i] sits in lane i (0..7)
      rp = fmaf(wm, Mv[i], rp);            // read uses PRE-update Mv
      float tp = fmaf(-ev, Mv[i], av);     // a - e*Mv
      Mv[i] = fmaf(wm, tp, Mv[i]);         // Mv += w*(a - e*Mv)
    }
    red[k * 256 + wave * 64 + lane] = rp;  // per-wave partial -> LDS
  }
}

// in-block reduce of a chunk: wave handles steps 2w, 2w+1; writes 1 partial per block
__device__ __forceinline__ void reduce_store(
    const float* __restrict__ red, int ch, int b, int s, int wave, int lane,
    float* __restrict__ part_ws)
{
  #pragma unroll
  for (int u = 0; u < 2; ++u) {
    const float* rr = red + (wave * 2 + u) * 256;
    const float v = (rr[lane] + rr[64 + lane]) + (rr[128 + lane] + rr[192 + lane]);
    const int t = ch * CH + wave * 2 + u;
    part_ws[((size_t)b * TT + t) * 128 + s * 64 + lane] = v;
  }
}

// Pass B: sequential scan; 2 blocks x 4 waves x 8 rows per batch; per-chunk in-block
// reduction (LDS red, double-buffered, 1 barrier/chunk) -> 2 partials/row (6.5 MB total).
__global__ __launch_bounds__(256) void scan_kernel(
    const float* __restrict__ Mv0,
    const float* __restrict__ w_ws, const float* __restrict__ e_ws,
    const float* __restrict__ a_ws, float* __restrict__ part_ws)
{
  __shared__ float red[2][CH * 256];                 // 16 KB
  const int b    = blockIdx.x >> 1;
  const int s    = blockIdx.x & 1;
  const int wave = threadIdx.x >> 6;
  const int lane = threadIdx.x & 63;
  const int m0   = s * 32 + wave * RW;
  const int wl   = m0 + (lane & (RW - 1));
  float Mv[RW];
  #pragma unroll
  for (int i = 0; i < RW; ++i) Mv[i] = Mv0[(size_t)(m0 + i) * 64 + lane];

  const float* wr = w_ws + (size_t)b * TT * 64;
  const float* er = e_ws + (size_t)b * TT * 64;
  const float* ar = a_ws + (size_t)b * TT * 64;

  float wb0[CH], eb0[CH], ab0[CH];
  float wb1[CH], eb1[CH], ab1[CH];
  load_chunk(wr, er, ar, 0, wl, lane, wb0, eb0, ab0);
  for (int ch = 0; ch < TT / CH; ch += 2) {
    if ((ch + 1) * CH < TT)
      load_chunk(wr, er, ar, (ch + 1) * CH, wl, lane, wb1, eb1, ab1);
    compute_chunk(Mv, wb0, eb0, ab0, red[0], wave, lane);
    __syncthreads();
    reduce_store(red[0], ch, b, s, wave, lane, part_ws);
    if ((ch + 2) * CH < TT)
      load_chunk(wr, er, ar, (ch + 2) * CH, wl, lane, wb0, eb0, ab0);
    if ((ch + 1) * CH < TT) {
      compute_chunk(Mv, wb1, eb1, ab1, red[1], wave, lane);
      __syncthreads();
      reduce_store(red[1], ch + 1, b, s, wave, lane, part_ws);
    }
  }
}

// Pass C: read = sum 2 partials; f = tanh([read,k] fW^T + fb); p = sigm(f pW + pb).
// fW f16-pair-packed in LDS (stride 72); inner loop = 1 readlane + 1 dot2 per 2 inputs.
__global__ __launch_bounds__(256) void fp_kernel(
    const int* __restrict__ skills, const float* __restrict__ k_emb,
    const float* __restrict__ fW, const float* __restrict__ fb,
    const float* __restrict__ pW, const float* __restrict__ pb,
    const float* __restrict__ part_ws, float* __restrict__ out)
{
  __shared__ unsigned sf[64 * 72];                   // 18432 B
  const int tid = threadIdx.x;
  for (int ch = tid; ch < 1024; ch += 256) {         // 16 8-input chunks per row
    const int j = ch >> 4, cc = ch & 15;
    const float4 f0 = ((const float4*)fW)[j * 32 + cc * 2];
    const float4 f1 = ((const float4*)fW)[j * 32 + cc * 2 + 1];
    uint4 pk;
    pk.x = pack2h(f0.x, f0.y); pk.y = pack2h(f0.z, f0.w);
    pk.z = pack2h(f1.x, f1.y); pk.w = pack2h(f1.z, f1.w);
    *(uint4*)&sf[j * 72 + ((cc + j) & 15) * 4] = pk;
  }
  __syncthreads();

  const int wave = tid >> 6, lane = tid & 63;
  const float fbl = fb[lane], pwl = pW[lane], pb0 = pb[0];
  const int p = blockIdx.x * 4 + wave;               // pair id, grid exact: 1592*4 = 6368

  float pc[2][2], kc[2];
  int bsave[2], tsave[2];
  #pragma unroll
  for (int i = 0; i < 2; ++i) {
    const unsigned idx = 2u * p + i;
    const unsigned b = idx / 199u;
    const int row = (int)(idx + b + 1u);
    bsave[i] = (int)b; tsave[i] = (int)(idx - b * 199u);
    const float* pp = part_ws + (size_t)row * 128;
    pc[i][0] = pp[lane]; pc[i][1] = pp[64 + lane];
    kc[i] = k_emb[(size_t)skills[row] * 64 + lane];
  }
  unsigned rvp[2], kvp[2];
  #pragma unroll
  for (int i = 0; i < 2; ++i) {
    rvp[i] = pack_pairs(pc[i][0] + pc[i][1]);
    kvp[i] = pack_pairs(kc[i]);
  }

  float acc[2] = {fbl, fbl};
  #pragma unroll 1
  for (int h = 0; h < 4; ++h) {                      // quarters: 4 uint4 (32 inputs) each
    uint4 qf[4];
    #pragma unroll
    for (int c = 0; c < 4; ++c)
      qf[c] = *(const uint4*)&sf[lane * 72 + (((h * 4 + c) + lane) & 15) * 4];
    #pragma unroll
    for (int i = 0; i < 2; ++i) {
      #pragma unroll
      for (int c = 0; c < 4; ++c) {
        const unsigned uu[4] = {qf[c].x, qf[c].y, qf[c].z, qf[c].w};
        #pragma unroll
        for (int m = 0; m < 4; ++m) {
          const int idx = (h * 4 + c) * 4 + m;       // pair index 0..63
          const unsigned sp = (idx < 32) ? ulane_bcast(rvp[i], idx)
                                         : ulane_bcast(kvp[i], idx - 32);
          acc[i] = dot2h(sp, uu[m], acc[i]);
        }
      }
    }
  }

  float f0 = tanh_fast(acc[0]) * pwl;
  float f1 = tanh_fast(acc[1]) * pwl;
  #pragma unroll
  for (int off = 32; off; off >>= 1) {
    f0 += __shfl_xor(f0, off);
    f1 += __shfl_xor(f1, off);
  }
  if (lane == 0) {
    out[(size_t)bsave[0] * (TT - 1) + tsave[0]] = sigm(f0 + pb0);
    out[(size_t)bsave[1] * (TT - 1) + tsave[1]] = sigm(f1 + pb0);
  }
}

extern "C" void kernel_launch(void* const* d_in, const int* in_sizes, int n_in,
                              void* d_out, int out_size, void* d_ws, size_t ws_size,
                              hipStream_t stream) {
  const int* skills    = (const int*)d_in[0];
  const int* responses = (const int*)d_in[1];
  const float* k_emb   = (const float*)d_in[2];
  const float* v_emb   = (const float*)d_in[3];
  const float* Mk      = (const float*)d_in[4];
  const float* Mv0     = (const float*)d_in[5];
  const float* fW      = (const float*)d_in[6];
  const float* fb      = (const float*)d_in[7];
  const float* eW      = (const float*)d_in[8];
  const float* eb      = (const float*)d_in[9];
  const float* aW      = (const float*)d_in[10];
  const float* ab      = (const float*)d_in[11];
  const float* pW      = (const float*)d_in[12];
  const float* pb      = (const float*)d_in[13];

  // fp32 scratch: w | e | a (B*T*64 each) | read-partials (B*T*128) ~= 16.4 MB
  float* w_ws    = (float*)d_ws;
  float* e_ws    = w_ws + (size_t)BB * TT * 64;
  float* a_ws    = e_ws + (size_t)BB * TT * 64;
  float* part_ws = a_ws + (size_t)BB * TT * 64;

  wea_kernel<<<dim3(NROW / 8), 256, 0, stream>>>(
      skills, responses, k_emb, v_emb, Mk, eW, eb, aW, ab, w_ws, e_ws, a_ws);
  scan_kernel<<<dim3(BB * 2), 256, 0, stream>>>(Mv0, w_ws, e_ws, a_ws, part_ws);
  fp_kernel<<<dim3(NOUT / 8), 256, 0, stream>>>(
      skills, k_emb, fW, fb, pW, pb, part_ws, (float*)d_out);
}